// Round 24
// baseline (350.807 us; speedup 1.0000x reference)
//
#include <hip/hip_runtime.h>
#include <hip/hip_bf16.h>

#define TPB  256
#define WPB  4              // waves per block
#define NBLK 512            // 2 blocks/CU (LDS now 3.6 KB -> co-residency unblocked?)

typedef short    short8 __attribute__((ext_vector_type(8)));
typedef float    f32x4  __attribute__((ext_vector_type(4)));
typedef unsigned uint4v __attribute__((ext_vector_type(4)));

#define SBAR() __builtin_amdgcn_sched_barrier(0)

struct Frag   { short8 k0, k1, k2, k3; };
struct Acc8   { f32x4 n0, n1, n2, n3, n4, n5, n6, n7; };
struct Acc8x6 { Acc8 a, b, c, d, e, f; };

__device__ __forceinline__ f32x4 sp4(float v) { f32x4 r = {v, v, v, v}; return r; }

__device__ __forceinline__ float fast_tanh(float z) {
    float e = __expf(2.0f * z);
    return 1.0f - 2.0f * __builtin_amdgcn_rcpf(e + 1.0f);
}
__device__ __forceinline__ f32x4 tanh4(f32x4 z) {
    f32x4 r;
    r[0] = fast_tanh(z[0]); r[1] = fast_tanh(z[1]);
    r[2] = fast_tanh(z[2]); r[3] = fast_tanh(z[3]);
    return r;
}

__device__ __forceinline__ unsigned short bf16_bits(float v) {
    __hip_bfloat16 b = __float2bfloat16(v);
    unsigned short s; __builtin_memcpy(&s, &b, 2);
    return s;
}
__device__ __forceinline__ unsigned pack_bf2(float lo, float hi) {
    return (unsigned)bf16_bits(lo) | ((unsigned)bf16_bits(hi) << 16);
}
__device__ __forceinline__ short8 packB(f32x4 lo, f32x4 hi) {
    uint4v u;
    u[0] = pack_bf2(lo[0], lo[1]);
    u[1] = pack_bf2(lo[2], lo[3]);
    u[2] = pack_bf2(hi[0], hi[1]);
    u[3] = pack_bf2(hi[2], hi[3]);
    return __builtin_bit_cast(short8, u);
}

__device__ __forceinline__ Acc8 acc_zero() {
    Acc8 A;
    A.n0 = sp4(0.f); A.n1 = sp4(0.f); A.n2 = sp4(0.f); A.n3 = sp4(0.f);
    A.n4 = sp4(0.f); A.n5 = sp4(0.f); A.n6 = sp4(0.f); A.n7 = sp4(0.f);
    return A;
}
__device__ __forceinline__ Acc8 acc_bias(const float* bp, int fb) {
    Acc8 A;
    A.n0 = *(const f32x4*)(bp + 0 * 16 + fb);
    A.n1 = *(const f32x4*)(bp + 1 * 16 + fb);
    A.n2 = *(const f32x4*)(bp + 2 * 16 + fb);
    A.n3 = *(const f32x4*)(bp + 3 * 16 + fb);
    A.n4 = *(const f32x4*)(bp + 4 * 16 + fb);
    A.n5 = *(const f32x4*)(bp + 5 * 16 + fb);
    A.n6 = *(const f32x4*)(bp + 6 * 16 + fb);
    A.n7 = *(const f32x4*)(bp + 7 * 16 + fb);
    return A;
}

// ---------------- kernel 1: build fragment-major bf16 panels in d_ws --------
// ws[p][frag=NT*4+KK][lane][j] = W_panel value the A-frag read wants.
// Each wave-level read of a frag is then 64 lanes x 16 B CONTIGUOUS (1 KB):
// perfectly coalesced, L2-resident (64 KB total, shared by all CUs).
__global__ void build_panels(const float* __restrict__ gW2,
                             const float* __restrict__ gW3,
                             unsigned short* __restrict__ ws) {
    int idx = blockIdx.x * blockDim.x + threadIdx.x;
    if (idx >= 2 * 16384) return;
    int p = idx >> 14, e = idx & 16383;
    int fidx = e >> 9;                 // NT*4+KK in [0,32)
    int rem  = e & 511;
    int lane = rem >> 3, j = rem & 7;
    int NT = fidx >> 2, KK = fidx & 3;
    int g = lane >> 4, c = lane & 15;
    int n  = NT * 16 + c;              // panel row (output feature)
    int pp = KK * 32 + g * 8 + j;      // sigma-permuted k position
    int kk = pp >> 5, gg = (pp >> 3) & 3, jj = pp & 7;
    int f = ((((jj >> 2) << 2) | kk) << 4) | (gg << 2) | (jj & 3);  // invsigma
    const float* Wsrc = p ? gW3 : gW2;
    ws[idx] = bf16_bits(Wsrc[f * 128 + n]);
}

// Hex GEMM sharing one A-panel pass: 32 coalesced 1-KB global reads (L2-hot)
// feed 192 MFMAs. SBAR per 8 rows caps the load-prefetch window (spill guard).
__device__ __forceinline__ Acc8x6 gemm6_frag(const unsigned short* __restrict__ gpnl,
                                             int lane8,
                                             Frag B0, Frag B1, Frag B2,
                                             Frag B3, Frag B4, Frag B5,
                                             Acc8 A0, Acc8 A1, Acc8 A2,
                                             Acc8 A3, Acc8 A4, Acc8 A5) {
#define ROW6(NT, N, KK, V0, V1, V2, V3, V4, V5) { \
    const short8 af = *reinterpret_cast<const short8*>( \
        gpnl + ((NT) * 4 + (KK)) * 512 + lane8); \
    A0.N = __builtin_amdgcn_mfma_f32_16x16x32_bf16(af, V0, A0.N, 0, 0, 0); \
    A1.N = __builtin_amdgcn_mfma_f32_16x16x32_bf16(af, V1, A1.N, 0, 0, 0); \
    A2.N = __builtin_amdgcn_mfma_f32_16x16x32_bf16(af, V2, A2.N, 0, 0, 0); \
    A3.N = __builtin_amdgcn_mfma_f32_16x16x32_bf16(af, V3, A3.N, 0, 0, 0); \
    A4.N = __builtin_amdgcn_mfma_f32_16x16x32_bf16(af, V4, A4.N, 0, 0, 0); \
    A5.N = __builtin_amdgcn_mfma_f32_16x16x32_bf16(af, V5, A5.N, 0, 0, 0); }
#define KS6(KK, V0, V1, V2, V3, V4, V5) \
    ROW6(0, n0, KK, V0, V1, V2, V3, V4, V5) ROW6(1, n1, KK, V0, V1, V2, V3, V4, V5) \
    ROW6(2, n2, KK, V0, V1, V2, V3, V4, V5) ROW6(3, n3, KK, V0, V1, V2, V3, V4, V5) \
    ROW6(4, n4, KK, V0, V1, V2, V3, V4, V5) ROW6(5, n5, KK, V0, V1, V2, V3, V4, V5) \
    ROW6(6, n6, KK, V0, V1, V2, V3, V4, V5) ROW6(7, n7, KK, V0, V1, V2, V3, V4, V5) SBAR();
    KS6(0, B0.k0, B1.k0, B2.k0, B3.k0, B4.k0, B5.k0)
    KS6(1, B0.k1, B1.k1, B2.k1, B3.k1, B4.k1, B5.k1)
    KS6(2, B0.k2, B1.k2, B2.k2, B3.k2, B4.k2, B5.k2)
    KS6(3, B0.k3, B1.k3, B2.k3, B3.k3, B4.k3, B5.k3)
#undef KS6
#undef ROW6
    Acc8x6 R; R.a = A0; R.b = A1; R.c = A2; R.d = A3; R.e = A4; R.f = A5; return R;
}

__device__ __forceinline__ float red16(float v) {
    v += __shfl_xor(v, 16, 64);
    v += __shfl_xor(v, 32, 64);
    return v;
}
__device__ __forceinline__ float hsum4(f32x4 v) {
    return (v[0] + v[1]) + (v[2] + v[3]);
}

// LDS = params only (3584 B) -> tests the hypothesis that 73-KB blocks could
// never co-reside (64-KB LDS base granularity: 0 -> next base 128 KB -> 128+71.5
// > 160). wpe(1,2): 256-reg target (no spill at peak ~310 unified w/ accs in
// AGPR-equivalents... VGPR_Count was 208-248 in this family), max 2 waves/SIMD.
__global__ __launch_bounds__(TPB, 1) __attribute__((amdgpu_waves_per_eu(1, 2)))
void mlp_jet_kernel(
    const float* __restrict__ X,
    const float* __restrict__ gW1, const float* __restrict__ gB1,
    const float* __restrict__ gB2, const float* __restrict__ gB3,
    const float* __restrict__ gW4, const float* __restrict__ gB4,
    const unsigned short* __restrict__ gPanel,
    float* __restrict__ out, int N)
{
    __shared__ alignas(16) float sParam[7 * 128];                    // 3584 B total LDS

    const int tid = threadIdx.x;
    if (tid < 128) {
        sParam[0 * 128 + tid] = gW1[tid];
        sParam[1 * 128 + tid] = gW1[128 + tid];
        sParam[2 * 128 + tid] = gW1[256 + tid];
        sParam[3 * 128 + tid] = gB1[tid];
        sParam[4 * 128 + tid] = gB2[tid];
        sParam[5 * 128 + tid] = gB3[tid];
        sParam[6 * 128 + tid] = gW4[tid];
    }
    __syncthreads();

    const int lane = tid & 63;
    const int wave = tid >> 6;
    const int g = lane >> 4;
    const int fb = g << 2;
    const int lane8 = lane * 8;
    const unsigned short* const pW2f = gPanel;
    const unsigned short* const pW3f = gPanel + 16384;
    const float b4 = gB4[0];
    const float* const w4p = sParam + 6 * 128;
    const int c = lane & 15;

    const int tiles = N >> 4;
    for (int t = blockIdx.x * WPB + wave; t < tiles; t += NBLK * WPB) {
        const int sbase = t << 4;
        const float* xp = X + (long)(sbase + c) * 3;
        const float xt = xp[0], xx = xp[1], xy = xp[2];

        // ---- FUSED layer-1 seeds (one pass, w-vectors loaded once) ----
        Frag h1F, t1t, t1x, t1y, s1x, s1y;
#define SEED(K, IL, IH) { \
    const int fL = (IL) * 16 + fb, fH = (IH) * 16 + fb; \
    f32x4 wtL = *(const f32x4*)(sParam + fL),        wtH = *(const f32x4*)(sParam + fH); \
    f32x4 wxL = *(const f32x4*)(sParam + 128 + fL),  wxH = *(const f32x4*)(sParam + 128 + fH); \
    f32x4 wyL = *(const f32x4*)(sParam + 256 + fL),  wyH = *(const f32x4*)(sParam + 256 + fH); \
    f32x4 bbL = *(const f32x4*)(sParam + 384 + fL),  bbH = *(const f32x4*)(sParam + 384 + fH); \
    f32x4 hL = tanh4(sp4(xt) * wtL + sp4(xx) * wxL + sp4(xy) * wyL + bbL); \
    f32x4 hH = tanh4(sp4(xt) * wtH + sp4(xx) * wxH + sp4(xy) * wyH + bbH); \
    f32x4 aL = sp4(1.f) - hL * hL, aH = sp4(1.f) - hH * hH; \
    h1F.K = packB(hL, hH); \
    t1t.K = packB(aL * wtL, aH * wtH); \
    t1x.K = packB(aL * wxL, aH * wxH); \
    t1y.K = packB(aL * wyL, aH * wyH); \
    s1x.K = packB((sp4(0.f) - hL) * aL * wxL * wxL, (sp4(0.f) - hH) * aH * wxH * wxH); \
    s1y.K = packB((sp4(0.f) - hL) * aL * wyL * wyL, (sp4(0.f) - hH) * aH * wyH * wyH); \
    SBAR(); }
        SEED(k0, 0, 4) SEED(k1, 1, 5) SEED(k2, 2, 6) SEED(k3, 3, 7)
#undef SEED

        // ---- layer 2 (ONE panel pass): z2 | tz2t | tz2x | tz2y | sz2x | sz2y ----
        Acc8x6 R6 = gemm6_frag(pW2f, lane8, h1F, t1t, t1x, t1y, s1x, s1y,
                               acc_bias(sParam + 4 * 128, fb),
                               acc_zero(), acc_zero(), acc_zero(),
                               acc_zero(), acc_zero());

        // ---- FUSED layer-2 post (one pass over 6 accs) ----
        Frag h2F, t2t, txF, tyF, s2xF, s2yF;
#define POST2(K, NL, NH) { \
    f32x4 hL = tanh4(R6.a.NL), hH = tanh4(R6.a.NH); \
    f32x4 aL = sp4(1.f) - hL * hL, aH = sp4(1.f) - hH * hH; \
    h2F.K = packB(hL, hH); \
    t2t.K = packB(aL * R6.b.NL, aH * R6.b.NH); \
    f32x4 txL = aL * R6.c.NL, txH = aH * R6.c.NH; \
    txF.K = packB(txL, txH); \
    f32x4 pxL = (sp4(0.f) - hL) * txL * R6.c.NL, pxH = (sp4(0.f) - hH) * txH * R6.c.NH; \
    f32x4 tyL = aL * R6.d.NL, tyH = aH * R6.d.NH; \
    tyF.K = packB(tyL, tyH); \
    f32x4 pyL = (sp4(0.f) - hL) * tyL * R6.d.NL, pyH = (sp4(0.f) - hH) * tyH * R6.d.NH; \
    s2xF.K = packB(aL * R6.e.NL + pxL, aH * R6.e.NH + pxH); \
    s2yF.K = packB(aL * R6.f.NL + pyL, aH * R6.f.NH + pyH); \
    SBAR(); }
        POST2(k0, n0, n4) POST2(k1, n1, n5) POST2(k2, n2, n6) POST2(k3, n3, n7)
#undef POST2

        // ---- layer 3 (ONE panel pass): z3 | tz3t | tz3x | tz3y | sz3x | sz3y ----
        R6 = gemm6_frag(pW3f, lane8, h2F, t2t, txF, tyF, s2xF, s2yF,
                        acc_bias(sParam + 5 * 128, fb),
                        acc_zero(), acc_zero(), acc_zero(),
                        acc_zero(), acc_zero());

        // ---- FUSED layer-3 dots ----
        {
            f32x4 scp = sp4(0.f), sc1t = sp4(0.f);
            f32x4 srxa = sp4(0.f), srxb = sp4(0.f);
            f32x4 srya = sp4(0.f), sryb = sp4(0.f);
            f32x4 sc2x = sp4(0.f), sc2y = sp4(0.f);
#define DOTS(NL, NH, IL, IH) { \
    f32x4 w4L = *(const f32x4*)(w4p + (IL) * 16 + fb); \
    f32x4 w4H = *(const f32x4*)(w4p + (IH) * 16 + fb); \
    f32x4 hL = tanh4(R6.a.NL), hH = tanh4(R6.a.NH); \
    f32x4 waL = w4L * (sp4(1.f) - hL * hL), waH = w4H * (sp4(1.f) - hH * hH); \
    scp  += w4L * hL + w4H * hH; \
    sc1t += waL * R6.b.NL + waH * R6.b.NH; \
    srxa += waL * R6.c.NL + waH * R6.c.NH; \
    srxb -= waL * hL * R6.c.NL * R6.c.NL + waH * hH * R6.c.NH * R6.c.NH; \
    srya += waL * R6.d.NL + waH * R6.d.NH; \
    sryb -= waL * hL * R6.d.NL * R6.d.NL + waH * hH * R6.d.NH * R6.d.NH; \
    sc2x += waL * R6.e.NL + waH * R6.e.NH; \
    sc2y += waL * R6.f.NL + waH * R6.f.NH; \
    SBAR(); }
            DOTS(n0, n4, 0, 4) DOTS(n1, n5, 1, 5) DOTS(n2, n6, 2, 6) DOTS(n3, n7, 3, 7)
#undef DOTS
            float cp  = red16(hsum4(scp));
            float c1t = red16(hsum4(sc1t));
            float c1x = red16(hsum4(srxa));
            float c1y = red16(hsum4(srya));
            float c2x = red16(hsum4(srxb) + hsum4(sc2x));
            float c2y = red16(hsum4(sryb) + hsum4(sc2y));
            if (lane < 16) {
                out[sbase + lane]           = cp + b4;
                out[(long)N + sbase + lane] = c1t;
                out[2L * N + sbase + lane]  = c1x;
                out[3L * N + sbase + lane]  = c1y;
                out[4L * N + sbase + lane]  = 2.f * c2x;
                out[5L * N + sbase + lane]  = 2.f * c2y;
            }
        }
    }
}

extern "C" void kernel_launch(void* const* d_in, const int* in_sizes, int n_in,
                              void* d_out, int out_size, void* d_ws, size_t ws_size,
                              hipStream_t stream) {
    const float* X  = (const float*)d_in[0];
    const float* W1 = (const float*)d_in[1];
    const float* B1 = (const float*)d_in[2];
    const float* W2 = (const float*)d_in[3];
    const float* B2 = (const float*)d_in[4];
    const float* W3 = (const float*)d_in[5];
    const float* B3 = (const float*)d_in[6];
    const float* W4 = (const float*)d_in[7];
    const float* B4 = (const float*)d_in[8];
    float* out = (float*)d_out;
    unsigned short* ws = (unsigned short*)d_ws;
    const int N = in_sizes[0] / 3;

    build_panels<<<(2 * 16384 + 255) / 256, 256, 0, stream>>>(W2, W3, ws);
    mlp_jet_kernel<<<NBLK, TPB, 0, stream>>>(X, W1, B1, B2, B3, W4, B4, ws, out, N);
}

// Round 25
// 151.709 us; speedup vs baseline: 2.3124x; 2.3124x over previous
//
#include <hip/hip_runtime.h>
#include <hip/hip_bf16.h>

#define TPB  256
#define WPB  4              // waves per block; 1 block/CU (serial regime)
#define NBLK 256
#define PROW 136            // panel row stride in shorts (272B = odd*16B)
#define PSZ  (128 * PROW)   // shorts per panel

typedef short    short8 __attribute__((ext_vector_type(8)));
typedef float    f32x4  __attribute__((ext_vector_type(4)));
typedef unsigned uint4v __attribute__((ext_vector_type(4)));

#define SBAR() __builtin_amdgcn_sched_barrier(0)

// No local arrays anywhere; named-member structs by value only.
struct Frag   { short8 k0, k1, k2, k3; };
struct Acc8   { f32x4 n0, n1, n2, n3, n4, n5, n6, n7; };
struct Acc8x6 { Acc8 a, b, c, d, e, f; };

__device__ __forceinline__ f32x4 sp4(float v) { f32x4 r = {v, v, v, v}; return r; }

__device__ __forceinline__ float fast_tanh(float z) {
    float e = __expf(2.0f * z);
    return 1.0f - 2.0f * __builtin_amdgcn_rcpf(e + 1.0f);
}
__device__ __forceinline__ f32x4 tanh4(f32x4 z) {
    f32x4 r;
    r[0] = fast_tanh(z[0]); r[1] = fast_tanh(z[1]);
    r[2] = fast_tanh(z[2]); r[3] = fast_tanh(z[3]);
    return r;
}

__device__ __forceinline__ unsigned short bf16_bits(float v) {
    __hip_bfloat16 b = __float2bfloat16(v);
    unsigned short s; __builtin_memcpy(&s, &b, 2);
    return s;
}
__device__ __forceinline__ unsigned pack_bf2(float lo, float hi) {
    return (unsigned)bf16_bits(lo) | ((unsigned)bf16_bits(hi) << 16);
}
__device__ __forceinline__ short8 packB(f32x4 lo, f32x4 hi) {
    uint4v u;
    u[0] = pack_bf2(lo[0], lo[1]);
    u[1] = pack_bf2(lo[2], lo[3]);
    u[2] = pack_bf2(hi[0], hi[1]);
    u[3] = pack_bf2(hi[2], hi[3]);
    return __builtin_bit_cast(short8, u);
}

__device__ __forceinline__ Acc8 acc_zero() {
    Acc8 A;
    A.n0 = sp4(0.f); A.n1 = sp4(0.f); A.n2 = sp4(0.f); A.n3 = sp4(0.f);
    A.n4 = sp4(0.f); A.n5 = sp4(0.f); A.n6 = sp4(0.f); A.n7 = sp4(0.f);
    return A;
}
__device__ __forceinline__ Acc8 acc_bias(const float* bp, int fb) {
    Acc8 A;
    A.n0 = *(const f32x4*)(bp + 0 * 16 + fb);
    A.n1 = *(const f32x4*)(bp + 1 * 16 + fb);
    A.n2 = *(const f32x4*)(bp + 2 * 16 + fb);
    A.n3 = *(const f32x4*)(bp + 3 * 16 + fb);
    A.n4 = *(const f32x4*)(bp + 4 * 16 + fb);
    A.n5 = *(const f32x4*)(bp + 5 * 16 + fb);
    A.n6 = *(const f32x4*)(bp + 6 * 16 + fb);
    A.n7 = *(const f32x4*)(bp + 7 * 16 + fb);
    return A;
}

// Hex GEMM sharing one A-panel pass: 32 A-frag reads feed 192 MFMAs (six
// B-streams). One pass per layer -> 64 panel reads/tile, zero jet-LDS traffic.
// The per-8-row SBARs here remain ESSENTIAL (R10: without them the scheduler
// hoists all 32 ds_reads -> 128-VGPR A-frag window -> catastrophic spill).
__device__ __forceinline__ Acc8x6 gemm6_frag(const unsigned short* __restrict__ pnl,
                                             int c, int g,
                                             Frag B0, Frag B1, Frag B2,
                                             Frag B3, Frag B4, Frag B5,
                                             Acc8 A0, Acc8 A1, Acc8 A2,
                                             Acc8 A3, Acc8 A4, Acc8 A5) {
#define ROW6(NT, N, KK, V0, V1, V2, V3, V4, V5) { \
    const short8 af = *reinterpret_cast<const short8*>( \
        pnl + ((NT) * 16 + c) * PROW + (KK) * 32 + g * 8); \
    A0.N = __builtin_amdgcn_mfma_f32_16x16x32_bf16(af, V0, A0.N, 0, 0, 0); \
    A1.N = __builtin_amdgcn_mfma_f32_16x16x32_bf16(af, V1, A1.N, 0, 0, 0); \
    A2.N = __builtin_amdgcn_mfma_f32_16x16x32_bf16(af, V2, A2.N, 0, 0, 0); \
    A3.N = __builtin_amdgcn_mfma_f32_16x16x32_bf16(af, V3, A3.N, 0, 0, 0); \
    A4.N = __builtin_amdgcn_mfma_f32_16x16x32_bf16(af, V4, A4.N, 0, 0, 0); \
    A5.N = __builtin_amdgcn_mfma_f32_16x16x32_bf16(af, V5, A5.N, 0, 0, 0); }
#define KS6(KK, V0, V1, V2, V3, V4, V5) \
    ROW6(0, n0, KK, V0, V1, V2, V3, V4, V5) ROW6(1, n1, KK, V0, V1, V2, V3, V4, V5) \
    ROW6(2, n2, KK, V0, V1, V2, V3, V4, V5) ROW6(3, n3, KK, V0, V1, V2, V3, V4, V5) \
    ROW6(4, n4, KK, V0, V1, V2, V3, V4, V5) ROW6(5, n5, KK, V0, V1, V2, V3, V4, V5) \
    ROW6(6, n6, KK, V0, V1, V2, V3, V4, V5) ROW6(7, n7, KK, V0, V1, V2, V3, V4, V5) SBAR();
    KS6(0, B0.k0, B1.k0, B2.k0, B3.k0, B4.k0, B5.k0)
    KS6(1, B0.k1, B1.k1, B2.k1, B3.k1, B4.k1, B5.k1)
    KS6(2, B0.k2, B1.k2, B2.k2, B3.k2, B4.k2, B5.k2)
    KS6(3, B0.k3, B1.k3, B2.k3, B3.k3, B4.k3, B5.k3)
#undef KS6
#undef ROW6
    Acc8x6 R; R.a = A0; R.b = A1; R.c = A2; R.d = A3; R.e = A4; R.f = A5; return R;
}

__device__ __forceinline__ float red16(float v) {
    v += __shfl_xor(v, 16, 64);
    v += __shfl_xor(v, 32, 64);
    return v;
}
__device__ __forceinline__ float hsum4(f32x4 v) {
    return (v[0] + v[1]) + (v[2] + v[3]);
}

__global__ __launch_bounds__(TPB, 1) __attribute__((amdgpu_waves_per_eu(1)))
void mlp_jet_kernel(
    const float* __restrict__ X,
    const float* __restrict__ gW1, const float* __restrict__ gB1,
    const float* __restrict__ gW2, const float* __restrict__ gB2,
    const float* __restrict__ gW3, const float* __restrict__ gB3,
    const float* __restrict__ gW4, const float* __restrict__ gB4,
    float* __restrict__ out, int N)
{
    __shared__ alignas(16) unsigned short sPanel[2 * PSZ];           // 69632 B
    __shared__ alignas(16) float sParam[7 * 128];                    // 3584 B -> 73216 total

    const int tid = threadIdx.x;
    for (int idx = tid; idx < 2 * 128 * 128; idx += TPB) {
        int p = idx >> 14, e = idx & 16383, n = e >> 7, pp = e & 127;
        int kk = pp >> 5, gg = (pp >> 3) & 3, jj = pp & 7;
        int f = ((((jj >> 2) << 2) | kk) << 4) | (gg << 2) | (jj & 3);  // invsigma
        const float* Wsrc = p ? gW3 : gW2;
        sPanel[p * PSZ + n * PROW + pp] = bf16_bits(Wsrc[f * 128 + n]);
    }
    if (tid < 128) {
        sParam[0 * 128 + tid] = gW1[tid];
        sParam[1 * 128 + tid] = gW1[128 + tid];
        sParam[2 * 128 + tid] = gW1[256 + tid];
        sParam[3 * 128 + tid] = gB1[tid];
        sParam[4 * 128 + tid] = gB2[tid];
        sParam[5 * 128 + tid] = gB3[tid];
        sParam[6 * 128 + tid] = gW4[tid];
    }
    __syncthreads();

    const int lane = tid & 63;
    const int wave = tid >> 6;
    const int c = lane & 15, g = lane >> 4;
    const int fb = g << 2;
    const unsigned short* const pW2f = sPanel;
    const unsigned short* const pW3f = sPanel + PSZ;
    const float b4 = gB4[0];
    const float* const w4p = sParam + 6 * 128;

    const int tiles = N >> 4;
    for (int t = blockIdx.x * WPB + wave; t < tiles; t += NBLK * WPB) {
        const int sbase = t << 4;
        const float* xp = X + (long)(sbase + c) * 3;
        const float xt = xp[0], xx = xp[1], xy = xp[2];

        // ---- FUSED layer-1 seeds. NO sched barriers here (R25): at 208 VGPR
        // with ~48 headroom, letting the scheduler interleave param ds_reads,
        // transcendentals and packs across quads buys single-wave ILP; the
        // spill-guard role of these barriers is obsolete.
        Frag h1F, t1t, t1x, t1y, s1x, s1y;
#define SEED(K, IL, IH) { \
    const int fL = (IL) * 16 + fb, fH = (IH) * 16 + fb; \
    f32x4 wtL = *(const f32x4*)(sParam + fL),        wtH = *(const f32x4*)(sParam + fH); \
    f32x4 wxL = *(const f32x4*)(sParam + 128 + fL),  wxH = *(const f32x4*)(sParam + 128 + fH); \
    f32x4 wyL = *(const f32x4*)(sParam + 256 + fL),  wyH = *(const f32x4*)(sParam + 256 + fH); \
    f32x4 bbL = *(const f32x4*)(sParam + 384 + fL),  bbH = *(const f32x4*)(sParam + 384 + fH); \
    f32x4 hL = tanh4(sp4(xt) * wtL + sp4(xx) * wxL + sp4(xy) * wyL + bbL); \
    f32x4 hH = tanh4(sp4(xt) * wtH + sp4(xx) * wxH + sp4(xy) * wyH + bbH); \
    f32x4 aL = sp4(1.f) - hL * hL, aH = sp4(1.f) - hH * hH; \
    h1F.K = packB(hL, hH); \
    t1t.K = packB(aL * wtL, aH * wtH); \
    t1x.K = packB(aL * wxL, aH * wxH); \
    t1y.K = packB(aL * wyL, aH * wyH); \
    s1x.K = packB((sp4(0.f) - hL) * aL * wxL * wxL, (sp4(0.f) - hH) * aH * wxH * wxH); \
    s1y.K = packB((sp4(0.f) - hL) * aL * wyL * wyL, (sp4(0.f) - hH) * aH * wyH * wyH); }
        SEED(k0, 0, 4) SEED(k1, 1, 5) SEED(k2, 2, 6) SEED(k3, 3, 7)
#undef SEED

        // ---- layer 2 (ONE panel pass): z2 | tz2t | tz2x | tz2y | sz2x | sz2y ----
        Acc8x6 R6 = gemm6_frag(pW2f, c, g, h1F, t1t, t1x, t1y, s1x, s1y,
                               acc_bias(sParam + 4 * 128, fb),
                               acc_zero(), acc_zero(), acc_zero(),
                               acc_zero(), acc_zero());

        // ---- FUSED layer-2 post (one pass over 6 accs; no barriers) ----
        Frag h2F, t2t, txF, tyF, s2xF, s2yF;
#define POST2(K, NL, NH) { \
    f32x4 hL = tanh4(R6.a.NL), hH = tanh4(R6.a.NH); \
    f32x4 aL = sp4(1.f) - hL * hL, aH = sp4(1.f) - hH * hH; \
    h2F.K = packB(hL, hH); \
    t2t.K = packB(aL * R6.b.NL, aH * R6.b.NH); \
    f32x4 txL = aL * R6.c.NL, txH = aH * R6.c.NH; \
    txF.K = packB(txL, txH); \
    f32x4 pxL = (sp4(0.f) - hL) * txL * R6.c.NL, pxH = (sp4(0.f) - hH) * txH * R6.c.NH; \
    f32x4 tyL = aL * R6.d.NL, tyH = aH * R6.d.NH; \
    tyF.K = packB(tyL, tyH); \
    f32x4 pyL = (sp4(0.f) - hL) * tyL * R6.d.NL, pyH = (sp4(0.f) - hH) * tyH * R6.d.NH; \
    s2xF.K = packB(aL * R6.e.NL + pxL, aH * R6.e.NH + pxH); \
    s2yF.K = packB(aL * R6.f.NL + pyL, aH * R6.f.NH + pyH); }
        POST2(k0, n0, n4) POST2(k1, n1, n5) POST2(k2, n2, n6) POST2(k3, n3, n7)
#undef POST2

        // ---- layer 3 (ONE panel pass): z3 | tz3t | tz3x | tz3y | sz3x | sz3y ----
        R6 = gemm6_frag(pW3f, c, g, h2F, t2t, txF, tyF, s2xF, s2yF,
                        acc_bias(sParam + 5 * 128, fb),
                        acc_zero(), acc_zero(), acc_zero(),
                        acc_zero(), acc_zero());

        // ---- FUSED layer-3 dots (one pass; no barriers) ----
        {
            f32x4 scp = sp4(0.f), sc1t = sp4(0.f);
            f32x4 srxa = sp4(0.f), srxb = sp4(0.f);
            f32x4 srya = sp4(0.f), sryb = sp4(0.f);
            f32x4 sc2x = sp4(0.f), sc2y = sp4(0.f);
#define DOTS(NL, NH, IL, IH) { \
    f32x4 w4L = *(const f32x4*)(w4p + (IL) * 16 + fb); \
    f32x4 w4H = *(const f32x4*)(w4p + (IH) * 16 + fb); \
    f32x4 hL = tanh4(R6.a.NL), hH = tanh4(R6.a.NH); \
    f32x4 waL = w4L * (sp4(1.f) - hL * hL), waH = w4H * (sp4(1.f) - hH * hH); \
    scp  += w4L * hL + w4H * hH; \
    sc1t += waL * R6.b.NL + waH * R6.b.NH; \
    f32x4 wtxL = waL * R6.c.NL, wtxH = waH * R6.c.NH; \
    srxa += wtxL + wtxH; \
    srxb -= wtxL * hL * R6.c.NL + wtxH * hH * R6.c.NH; \
    f32x4 wtyL = waL * R6.d.NL, wtyH = waH * R6.d.NH; \
    srya += wtyL + wtyH; \
    sryb -= wtyL * hL * R6.d.NL + wtyH * hH * R6.d.NH; \
    sc2x += waL * R6.e.NL + waH * R6.e.NH; \
    sc2y += waL * R6.f.NL + waH * R6.f.NH; }
            DOTS(n0, n4, 0, 4) DOTS(n1, n5, 1, 5) DOTS(n2, n6, 2, 6) DOTS(n3, n7, 3, 7)
#undef DOTS
            float cp  = red16(hsum4(scp));
            float c1t = red16(hsum4(sc1t));
            float c1x = red16(hsum4(srxa));
            float c1y = red16(hsum4(srya));
            float c2x = red16(hsum4(srxb) + hsum4(sc2x));
            float c2y = red16(hsum4(sryb) + hsum4(sc2y));
            if (lane < 16) {
                out[sbase + lane]           = cp + b4;
                out[(long)N + sbase + lane] = c1t;
                out[2L * N + sbase + lane]  = c1x;
                out[3L * N + sbase + lane]  = c1y;
                out[4L * N + sbase + lane]  = 2.f * c2x;
                out[5L * N + sbase + lane]  = 2.f * c2y;
            }
        }
    }
}

extern "C" void kernel_launch(void* const* d_in, const int* in_sizes, int n_in,
                              void* d_out, int out_size, void* d_ws, size_t ws_size,
                              hipStream_t stream) {
    const float* X  = (const float*)d_in[0];
    const float* W1 = (const float*)d_in[1];
    const float* B1 = (const float*)d_in[2];
    const float* W2 = (const float*)d_in[3];
    const float* B2 = (const float*)d_in[4];
    const float* W3 = (const float*)d_in[5];
    const float* B3 = (const float*)d_in[6];
    const float* W4 = (const float*)d_in[7];
    const float* B4 = (const float*)d_in[8];
    float* out = (float*)d_out;
    const int N = in_sizes[0] / 3;

    mlp_jet_kernel<<<NBLK, TPB, 0, stream>>>(X, W1, B1, W2, B2, W3, B3, W4, B4, out, N);
}

// Round 26
// 134.830 us; speedup vs baseline: 2.6019x; 1.1252x over previous
//
#include <hip/hip_runtime.h>
#include <hip/hip_bf16.h>

#define TPB  256
#define WPB  4              // waves per block; 1 block/CU (serial regime)
#define NBLK 256
#define PROW 136            // panel row stride in shorts (272B = odd*16B)
#define PSZ  (128 * PROW)   // shorts per panel

typedef short    short8 __attribute__((ext_vector_type(8)));
typedef float    f32x4  __attribute__((ext_vector_type(4)));
typedef unsigned uint4v __attribute__((ext_vector_type(4)));

#define SBAR() __builtin_amdgcn_sched_barrier(0)

// No local arrays anywhere; named-member structs by value only.
struct Frag   { short8 k0, k1, k2, k3; };
struct Acc8   { f32x4 n0, n1, n2, n3, n4, n5, n6, n7; };
struct Acc8x6 { Acc8 a, b, c, d, e, f; };

__device__ __forceinline__ f32x4 sp4(float v) { f32x4 r = {v, v, v, v}; return r; }

__device__ __forceinline__ float fast_tanh(float z) {
    float e = __expf(2.0f * z);
    return 1.0f - 2.0f * __builtin_amdgcn_rcpf(e + 1.0f);
}
__device__ __forceinline__ f32x4 tanh4(f32x4 z) {
    f32x4 r;
    r[0] = fast_tanh(z[0]); r[1] = fast_tanh(z[1]);
    r[2] = fast_tanh(z[2]); r[3] = fast_tanh(z[3]);
    return r;
}

__device__ __forceinline__ unsigned short bf16_bits(float v) {
    __hip_bfloat16 b = __float2bfloat16(v);
    unsigned short s; __builtin_memcpy(&s, &b, 2);
    return s;
}
// HW packed convert: dst.lo16 = bf16(lo), dst.hi16 = bf16(hi), RNE — one
// instruction vs ~10 for the __float2bfloat16 pair+merge (48 packB/tile:
// this is the single largest VALU consumer if the compiler doesn't already
// pattern-match it; no builtin on gfx950, inline asm required [m240]).
__device__ __forceinline__ unsigned pack_bf2(float lo, float hi) {
    unsigned r;
    asm("v_cvt_pk_bf16_f32 %0, %1, %2" : "=v"(r) : "v"(lo), "v"(hi));
    return r;
}
__device__ __forceinline__ short8 packB(f32x4 lo, f32x4 hi) {
    uint4v u;
    u[0] = pack_bf2(lo[0], lo[1]);
    u[1] = pack_bf2(lo[2], lo[3]);
    u[2] = pack_bf2(hi[0], hi[1]);
    u[3] = pack_bf2(hi[2], hi[3]);
    return __builtin_bit_cast(short8, u);
}

__device__ __forceinline__ Acc8 acc_zero() {
    Acc8 A;
    A.n0 = sp4(0.f); A.n1 = sp4(0.f); A.n2 = sp4(0.f); A.n3 = sp4(0.f);
    A.n4 = sp4(0.f); A.n5 = sp4(0.f); A.n6 = sp4(0.f); A.n7 = sp4(0.f);
    return A;
}
__device__ __forceinline__ Acc8 acc_bias(const float* bp, int fb) {
    Acc8 A;
    A.n0 = *(const f32x4*)(bp + 0 * 16 + fb);
    A.n1 = *(const f32x4*)(bp + 1 * 16 + fb);
    A.n2 = *(const f32x4*)(bp + 2 * 16 + fb);
    A.n3 = *(const f32x4*)(bp + 3 * 16 + fb);
    A.n4 = *(const f32x4*)(bp + 4 * 16 + fb);
    A.n5 = *(const f32x4*)(bp + 5 * 16 + fb);
    A.n6 = *(const f32x4*)(bp + 6 * 16 + fb);
    A.n7 = *(const f32x4*)(bp + 7 * 16 + fb);
    return A;
}

// Hex GEMM sharing one A-panel pass: 32 A-frag reads feed 192 MFMAs (six
// B-streams). One pass per layer -> 64 panel reads/tile, zero jet-LDS traffic.
// Per-8-row SBARs remain ESSENTIAL (R10: without them the scheduler hoists
// all 32 ds_reads -> 128-VGPR A-frag window -> catastrophic spill).
__device__ __forceinline__ Acc8x6 gemm6_frag(const unsigned short* __restrict__ pnl,
                                             int c, int g,
                                             Frag B0, Frag B1, Frag B2,
                                             Frag B3, Frag B4, Frag B5,
                                             Acc8 A0, Acc8 A1, Acc8 A2,
                                             Acc8 A3, Acc8 A4, Acc8 A5) {
#define ROW6(NT, N, KK, V0, V1, V2, V3, V4, V5) { \
    const short8 af = *reinterpret_cast<const short8*>( \
        pnl + ((NT) * 16 + c) * PROW + (KK) * 32 + g * 8); \
    A0.N = __builtin_amdgcn_mfma_f32_16x16x32_bf16(af, V0, A0.N, 0, 0, 0); \
    A1.N = __builtin_amdgcn_mfma_f32_16x16x32_bf16(af, V1, A1.N, 0, 0, 0); \
    A2.N = __builtin_amdgcn_mfma_f32_16x16x32_bf16(af, V2, A2.N, 0, 0, 0); \
    A3.N = __builtin_amdgcn_mfma_f32_16x16x32_bf16(af, V3, A3.N, 0, 0, 0); \
    A4.N = __builtin_amdgcn_mfma_f32_16x16x32_bf16(af, V4, A4.N, 0, 0, 0); \
    A5.N = __builtin_amdgcn_mfma_f32_16x16x32_bf16(af, V5, A5.N, 0, 0, 0); }
#define KS6(KK, V0, V1, V2, V3, V4, V5) \
    ROW6(0, n0, KK, V0, V1, V2, V3, V4, V5) ROW6(1, n1, KK, V0, V1, V2, V3, V4, V5) \
    ROW6(2, n2, KK, V0, V1, V2, V3, V4, V5) ROW6(3, n3, KK, V0, V1, V2, V3, V4, V5) \
    ROW6(4, n4, KK, V0, V1, V2, V3, V4, V5) ROW6(5, n5, KK, V0, V1, V2, V3, V4, V5) \
    ROW6(6, n6, KK, V0, V1, V2, V3, V4, V5) ROW6(7, n7, KK, V0, V1, V2, V3, V4, V5) SBAR();
    KS6(0, B0.k0, B1.k0, B2.k0, B3.k0, B4.k0, B5.k0)
    KS6(1, B0.k1, B1.k1, B2.k1, B3.k1, B4.k1, B5.k1)
    KS6(2, B0.k2, B1.k2, B2.k2, B3.k2, B4.k2, B5.k2)
    KS6(3, B0.k3, B1.k3, B2.k3, B3.k3, B4.k3, B5.k3)
#undef KS6
#undef ROW6
    Acc8x6 R; R.a = A0; R.b = A1; R.c = A2; R.d = A3; R.e = A4; R.f = A5; return R;
}

__device__ __forceinline__ float red16(float v) {
    v += __shfl_xor(v, 16, 64);
    v += __shfl_xor(v, 32, 64);
    return v;
}
__device__ __forceinline__ float hsum4(f32x4 v) {
    return (v[0] + v[1]) + (v[2] + v[3]);
}

__global__ __launch_bounds__(TPB, 1) __attribute__((amdgpu_waves_per_eu(1)))
void mlp_jet_kernel(
    const float* __restrict__ X,
    const float* __restrict__ gW1, const float* __restrict__ gB1,
    const float* __restrict__ gW2, const float* __restrict__ gB2,
    const float* __restrict__ gW3, const float* __restrict__ gB3,
    const float* __restrict__ gW4, const float* __restrict__ gB4,
    float* __restrict__ out, int N)
{
    __shared__ alignas(16) unsigned short sPanel[2 * PSZ];           // 69632 B
    __shared__ alignas(16) float sParam[7 * 128];                    // 3584 B -> 73216 total

    const int tid = threadIdx.x;
    for (int idx = tid; idx < 2 * 128 * 128; idx += TPB) {
        int p = idx >> 14, e = idx & 16383, n = e >> 7, pp = e & 127;
        int kk = pp >> 5, gg = (pp >> 3) & 3, jj = pp & 7;
        int f = ((((jj >> 2) << 2) | kk) << 4) | (gg << 2) | (jj & 3);  // invsigma
        const float* Wsrc = p ? gW3 : gW2;
        sPanel[p * PSZ + n * PROW + pp] = bf16_bits(Wsrc[f * 128 + n]);
    }
    if (tid < 128) {
        sParam[0 * 128 + tid] = gW1[tid];
        sParam[1 * 128 + tid] = gW1[128 + tid];
        sParam[2 * 128 + tid] = gW1[256 + tid];
        sParam[3 * 128 + tid] = gB1[tid];
        sParam[4 * 128 + tid] = gB2[tid];
        sParam[5 * 128 + tid] = gB3[tid];
        sParam[6 * 128 + tid] = gW4[tid];
    }
    __syncthreads();

    const int lane = tid & 63;
    const int wave = tid >> 6;
    const int c = lane & 15, g = lane >> 4;
    const int fb = g << 2;
    const unsigned short* const pW2f = sPanel;
    const unsigned short* const pW3f = sPanel + PSZ;
    const float b4 = gB4[0];
    const float* const w4p = sParam + 6 * 128;

    const int tiles = N >> 4;
    for (int t = blockIdx.x * WPB + wave; t < tiles; t += NBLK * WPB) {
        const int sbase = t << 4;
        const float* xp = X + (long)(sbase + c) * 3;
        const float xt = xp[0], xx = xp[1], xy = xp[2];

        // ---- FUSED layer-1 seeds (no barriers; R25) ----
        Frag h1F, t1t, t1x, t1y, s1x, s1y;
#define SEED(K, IL, IH) { \
    const int fL = (IL) * 16 + fb, fH = (IH) * 16 + fb; \
    f32x4 wtL = *(const f32x4*)(sParam + fL),        wtH = *(const f32x4*)(sParam + fH); \
    f32x4 wxL = *(const f32x4*)(sParam + 128 + fL),  wxH = *(const f32x4*)(sParam + 128 + fH); \
    f32x4 wyL = *(const f32x4*)(sParam + 256 + fL),  wyH = *(const f32x4*)(sParam + 256 + fH); \
    f32x4 bbL = *(const f32x4*)(sParam + 384 + fL),  bbH = *(const f32x4*)(sParam + 384 + fH); \
    f32x4 hL = tanh4(sp4(xt) * wtL + sp4(xx) * wxL + sp4(xy) * wyL + bbL); \
    f32x4 hH = tanh4(sp4(xt) * wtH + sp4(xx) * wxH + sp4(xy) * wyH + bbH); \
    f32x4 aL = sp4(1.f) - hL * hL, aH = sp4(1.f) - hH * hH; \
    h1F.K = packB(hL, hH); \
    t1t.K = packB(aL * wtL, aH * wtH); \
    t1x.K = packB(aL * wxL, aH * wxH); \
    t1y.K = packB(aL * wyL, aH * wyH); \
    s1x.K = packB((sp4(0.f) - hL) * aL * wxL * wxL, (sp4(0.f) - hH) * aH * wxH * wxH); \
    s1y.K = packB((sp4(0.f) - hL) * aL * wyL * wyL, (sp4(0.f) - hH) * aH * wyH * wyH); }
        SEED(k0, 0, 4) SEED(k1, 1, 5) SEED(k2, 2, 6) SEED(k3, 3, 7)
#undef SEED

        // ---- layer 2 (ONE panel pass): z2 | tz2t | tz2x | tz2y | sz2x | sz2y ----
        Acc8x6 R6 = gemm6_frag(pW2f, c, g, h1F, t1t, t1x, t1y, s1x, s1y,
                               acc_bias(sParam + 4 * 128, fb),
                               acc_zero(), acc_zero(), acc_zero(),
                               acc_zero(), acc_zero());

        // ---- FUSED layer-2 post (one pass over 6 accs) ----
        Frag h2F, t2t, txF, tyF, s2xF, s2yF;
#define POST2(K, NL, NH) { \
    f32x4 hL = tanh4(R6.a.NL), hH = tanh4(R6.a.NH); \
    f32x4 aL = sp4(1.f) - hL * hL, aH = sp4(1.f) - hH * hH; \
    h2F.K = packB(hL, hH); \
    t2t.K = packB(aL * R6.b.NL, aH * R6.b.NH); \
    f32x4 txL = aL * R6.c.NL, txH = aH * R6.c.NH; \
    txF.K = packB(txL, txH); \
    f32x4 pxL = (sp4(0.f) - hL) * txL * R6.c.NL, pxH = (sp4(0.f) - hH) * txH * R6.c.NH; \
    f32x4 tyL = aL * R6.d.NL, tyH = aH * R6.d.NH; \
    tyF.K = packB(tyL, tyH); \
    f32x4 pyL = (sp4(0.f) - hL) * tyL * R6.d.NL, pyH = (sp4(0.f) - hH) * tyH * R6.d.NH; \
    s2xF.K = packB(aL * R6.e.NL + pxL, aH * R6.e.NH + pxH); \
    s2yF.K = packB(aL * R6.f.NL + pyL, aH * R6.f.NH + pyH); }
        POST2(k0, n0, n4) POST2(k1, n1, n5) POST2(k2, n2, n6) POST2(k3, n3, n7)
#undef POST2

        // ---- layer 3 (ONE panel pass): z3 | tz3t | tz3x | tz3y | sz3x | sz3y ----
        R6 = gemm6_frag(pW3f, c, g, h2F, t2t, txF, tyF, s2xF, s2yF,
                        acc_bias(sParam + 5 * 128, fb),
                        acc_zero(), acc_zero(), acc_zero(),
                        acc_zero(), acc_zero());

        // ---- FUSED layer-3 dots (one pass) ----
        {
            f32x4 scp = sp4(0.f), sc1t = sp4(0.f);
            f32x4 srxa = sp4(0.f), srxb = sp4(0.f);
            f32x4 srya = sp4(0.f), sryb = sp4(0.f);
            f32x4 sc2x = sp4(0.f), sc2y = sp4(0.f);
#define DOTS(NL, NH, IL, IH) { \
    f32x4 w4L = *(const f32x4*)(w4p + (IL) * 16 + fb); \
    f32x4 w4H = *(const f32x4*)(w4p + (IH) * 16 + fb); \
    f32x4 hL = tanh4(R6.a.NL), hH = tanh4(R6.a.NH); \
    f32x4 waL = w4L * (sp4(1.f) - hL * hL), waH = w4H * (sp4(1.f) - hH * hH); \
    scp  += w4L * hL + w4H * hH; \
    sc1t += waL * R6.b.NL + waH * R6.b.NH; \
    f32x4 wtxL = waL * R6.c.NL, wtxH = waH * R6.c.NH; \
    srxa += wtxL + wtxH; \
    srxb -= wtxL * hL * R6.c.NL + wtxH * hH * R6.c.NH; \
    f32x4 wtyL = waL * R6.d.NL, wtyH = waH * R6.d.NH; \
    srya += wtyL + wtyH; \
    sryb -= wtyL * hL * R6.d.NL + wtyH * hH * R6.d.NH; \
    sc2x += waL * R6.e.NL + waH * R6.e.NH; \
    sc2y += waL * R6.f.NL + waH * R6.f.NH; }
            DOTS(n0, n4, 0, 4) DOTS(n1, n5, 1, 5) DOTS(n2, n6, 2, 6) DOTS(n3, n7, 3, 7)
#undef DOTS
            float cp  = red16(hsum4(scp));
            float c1t = red16(hsum4(sc1t));
            float c1x = red16(hsum4(srxa));
            float c1y = red16(hsum4(srya));
            float c2x = red16(hsum4(srxb) + hsum4(sc2x));
            float c2y = red16(hsum4(sryb) + hsum4(sc2y));
            if (lane < 16) {
                out[sbase + lane]           = cp + b4;
                out[(long)N + sbase + lane] = c1t;
                out[2L * N + sbase + lane]  = c1x;
                out[3L * N + sbase + lane]  = c1y;
                out[4L * N + sbase + lane]  = 2.f * c2x;
                out[5L * N + sbase + lane]  = 2.f * c2y;
            }
        }
    }
}

extern "C" void kernel_launch(void* const* d_in, const int* in_sizes, int n_in,
                              void* d_out, int out_size, void* d_ws, size_t ws_size,
                              hipStream_t stream) {
    const float* X  = (const float*)d_in[0];
    const float* W1 = (const float*)d_in[1];
    const float* B1 = (const float*)d_in[2];
    const float* W2 = (const float*)d_in[3];
    const float* B2 = (const float*)d_in[4];
    const float* W3 = (const float*)d_in[5];
    const float* B3 = (const float*)d_in[6];
    const float* W4 = (const float*)d_in[7];
    const float* B4 = (const float*)d_in[8];
    float* out = (float*)d_out;
    const int N = in_sizes[0] / 3;

    mlp_jet_kernel<<<NBLK, TPB, 0, stream>>>(X, W1, B1, W2, B2, W3, B3, W4, B4, out, N);
}

// Round 27
// 134.002 us; speedup vs baseline: 2.6179x; 1.0062x over previous
//
#include <hip/hip_runtime.h>
#include <hip/hip_bf16.h>

#define TPB  256
#define WPB  4              // waves per block; 1 block/CU (serial regime)
#define NBLK 256
#define PROW 136            // panel row stride in shorts (272B = odd*16B)
#define PSZ  (128 * PROW)   // shorts per panel

typedef short    short8 __attribute__((ext_vector_type(8)));
typedef float    f32x4  __attribute__((ext_vector_type(4)));
typedef unsigned uint4v __attribute__((ext_vector_type(4)));

#define SBAR() __builtin_amdgcn_sched_barrier(0)

// No local arrays anywhere; named-member structs by value only.
struct Frag   { short8 k0, k1, k2, k3; };
struct Acc8   { f32x4 n0, n1, n2, n3, n4, n5, n6, n7; };
struct Acc8x6 { Acc8 a, b, c, d, e, f; };

__device__ __forceinline__ f32x4 sp4(float v) { f32x4 r = {v, v, v, v}; return r; }

__device__ __forceinline__ float fast_tanh(float z) {
    float e = __expf(2.0f * z);
    return 1.0f - 2.0f * __builtin_amdgcn_rcpf(e + 1.0f);
}
__device__ __forceinline__ f32x4 tanh4(f32x4 z) {
    f32x4 r;
    r[0] = fast_tanh(z[0]); r[1] = fast_tanh(z[1]);
    r[2] = fast_tanh(z[2]); r[3] = fast_tanh(z[3]);
    return r;
}

__device__ __forceinline__ unsigned short bf16_bits(float v) {
    __hip_bfloat16 b = __float2bfloat16(v);
    unsigned short s; __builtin_memcpy(&s, &b, 2);
    return s;
}
// HW packed convert (R26: -11%; compiler does NOT pattern-match this).
__device__ __forceinline__ unsigned pack_bf2(float lo, float hi) {
    unsigned r;
    asm("v_cvt_pk_bf16_f32 %0, %1, %2" : "=v"(r) : "v"(lo), "v"(hi));
    return r;
}
__device__ __forceinline__ short8 packB(f32x4 lo, f32x4 hi) {
    uint4v u;
    u[0] = pack_bf2(lo[0], lo[1]);
    u[1] = pack_bf2(lo[2], lo[3]);
    u[2] = pack_bf2(hi[0], hi[1]);
    u[3] = pack_bf2(hi[2], hi[3]);
    return __builtin_bit_cast(short8, u);
}

__device__ __forceinline__ Acc8 acc_zero() {
    Acc8 A;
    A.n0 = sp4(0.f); A.n1 = sp4(0.f); A.n2 = sp4(0.f); A.n3 = sp4(0.f);
    A.n4 = sp4(0.f); A.n5 = sp4(0.f); A.n6 = sp4(0.f); A.n7 = sp4(0.f);
    return A;
}
__device__ __forceinline__ Acc8 acc_bias(const float* bp, int fb) {
    Acc8 A;
    A.n0 = *(const f32x4*)(bp + 0 * 16 + fb);
    A.n1 = *(const f32x4*)(bp + 1 * 16 + fb);
    A.n2 = *(const f32x4*)(bp + 2 * 16 + fb);
    A.n3 = *(const f32x4*)(bp + 3 * 16 + fb);
    A.n4 = *(const f32x4*)(bp + 4 * 16 + fb);
    A.n5 = *(const f32x4*)(bp + 5 * 16 + fb);
    A.n6 = *(const f32x4*)(bp + 6 * 16 + fb);
    A.n7 = *(const f32x4*)(bp + 7 * 16 + fb);
    return A;
}

// Hex GEMM sharing one A-panel pass: 32 A-frag reads feed 192 MFMAs.
// R27: SBAR per TWO KS6 groups (16-read / 64-VGPR prefetch window, was 8/32).
// At 1 wave/SIMD there is no TLP to hide the ds_read->MFMA latency at window
// boundaries; deeper read-ahead covers it. 212+32 VGPR stays under the 256
// no-spill budget (WRITE_SIZE is the revert gate).
__device__ __forceinline__ Acc8x6 gemm6_frag(const unsigned short* __restrict__ pnl,
                                             int c, int g,
                                             Frag B0, Frag B1, Frag B2,
                                             Frag B3, Frag B4, Frag B5,
                                             Acc8 A0, Acc8 A1, Acc8 A2,
                                             Acc8 A3, Acc8 A4, Acc8 A5) {
#define ROW6(NT, N, KK, V0, V1, V2, V3, V4, V5) { \
    const short8 af = *reinterpret_cast<const short8*>( \
        pnl + ((NT) * 16 + c) * PROW + (KK) * 32 + g * 8); \
    A0.N = __builtin_amdgcn_mfma_f32_16x16x32_bf16(af, V0, A0.N, 0, 0, 0); \
    A1.N = __builtin_amdgcn_mfma_f32_16x16x32_bf16(af, V1, A1.N, 0, 0, 0); \
    A2.N = __builtin_amdgcn_mfma_f32_16x16x32_bf16(af, V2, A2.N, 0, 0, 0); \
    A3.N = __builtin_amdgcn_mfma_f32_16x16x32_bf16(af, V3, A3.N, 0, 0, 0); \
    A4.N = __builtin_amdgcn_mfma_f32_16x16x32_bf16(af, V4, A4.N, 0, 0, 0); \
    A5.N = __builtin_amdgcn_mfma_f32_16x16x32_bf16(af, V5, A5.N, 0, 0, 0); }
#define KS6(KK, V0, V1, V2, V3, V4, V5) \
    ROW6(0, n0, KK, V0, V1, V2, V3, V4, V5) ROW6(1, n1, KK, V0, V1, V2, V3, V4, V5) \
    ROW6(2, n2, KK, V0, V1, V2, V3, V4, V5) ROW6(3, n3, KK, V0, V1, V2, V3, V4, V5) \
    ROW6(4, n4, KK, V0, V1, V2, V3, V4, V5) ROW6(5, n5, KK, V0, V1, V2, V3, V4, V5) \
    ROW6(6, n6, KK, V0, V1, V2, V3, V4, V5) ROW6(7, n7, KK, V0, V1, V2, V3, V4, V5)
    KS6(0, B0.k0, B1.k0, B2.k0, B3.k0, B4.k0, B5.k0)
    KS6(1, B0.k1, B1.k1, B2.k1, B3.k1, B4.k1, B5.k1)
    SBAR();
    KS6(2, B0.k2, B1.k2, B2.k2, B3.k2, B4.k2, B5.k2)
    KS6(3, B0.k3, B1.k3, B2.k3, B3.k3, B4.k3, B5.k3)
    SBAR();
#undef KS6
#undef ROW6
    Acc8x6 R; R.a = A0; R.b = A1; R.c = A2; R.d = A3; R.e = A4; R.f = A5; return R;
}

__device__ __forceinline__ float red16(float v) {
    v += __shfl_xor(v, 16, 64);
    v += __shfl_xor(v, 32, 64);
    return v;
}
__device__ __forceinline__ float hsum4(f32x4 v) {
    return (v[0] + v[1]) + (v[2] + v[3]);
}

__global__ __launch_bounds__(TPB, 1) __attribute__((amdgpu_waves_per_eu(1)))
void mlp_jet_kernel(
    const float* __restrict__ X,
    const float* __restrict__ gW1, const float* __restrict__ gB1,
    const float* __restrict__ gW2, const float* __restrict__ gB2,
    const float* __restrict__ gW3, const float* __restrict__ gB3,
    const float* __restrict__ gW4, const float* __restrict__ gB4,
    float* __restrict__ out, int N)
{
    __shared__ alignas(16) unsigned short sPanel[2 * PSZ];           // 69632 B
    __shared__ alignas(16) float sParam[7 * 128];                    // 3584 B -> 73216 total

    const int tid = threadIdx.x;
    for (int idx = tid; idx < 2 * 128 * 128; idx += TPB) {
        int p = idx >> 14, e = idx & 16383, n = e >> 7, pp = e & 127;
        int kk = pp >> 5, gg = (pp >> 3) & 3, jj = pp & 7;
        int f = ((((jj >> 2) << 2) | kk) << 4) | (gg << 2) | (jj & 3);  // invsigma
        const float* Wsrc = p ? gW3 : gW2;
        sPanel[p * PSZ + n * PROW + pp] = bf16_bits(Wsrc[f * 128 + n]);
    }
    if (tid < 128) {
        sParam[0 * 128 + tid] = gW1[tid];
        sParam[1 * 128 + tid] = gW1[128 + tid];
        sParam[2 * 128 + tid] = gW1[256 + tid];
        sParam[3 * 128 + tid] = gB1[tid];
        sParam[4 * 128 + tid] = gB2[tid];
        sParam[5 * 128 + tid] = gB3[tid];
        sParam[6 * 128 + tid] = gW4[tid];
    }
    __syncthreads();

    const int lane = tid & 63;
    const int wave = tid >> 6;
    const int c = lane & 15, g = lane >> 4;
    const int fb = g << 2;
    const unsigned short* const pW2f = sPanel;
    const unsigned short* const pW3f = sPanel + PSZ;
    const float b4 = gB4[0];
    const float* const w4p = sParam + 6 * 128;

    const int tiles = N >> 4;
    for (int t = blockIdx.x * WPB + wave; t < tiles; t += NBLK * WPB) {
        const int sbase = t << 4;
        const float* xp = X + (long)(sbase + c) * 3;
        const float xt = xp[0], xx = xp[1], xy = xp[2];

        // ---- FUSED layer-1 seeds (no barriers; R25) ----
        Frag h1F, t1t, t1x, t1y, s1x, s1y;
#define SEED(K, IL, IH) { \
    const int fL = (IL) * 16 + fb, fH = (IH) * 16 + fb; \
    f32x4 wtL = *(const f32x4*)(sParam + fL),        wtH = *(const f32x4*)(sParam + fH); \
    f32x4 wxL = *(const f32x4*)(sParam + 128 + fL),  wxH = *(const f32x4*)(sParam + 128 + fH); \
    f32x4 wyL = *(const f32x4*)(sParam + 256 + fL),  wyH = *(const f32x4*)(sParam + 256 + fH); \
    f32x4 bbL = *(const f32x4*)(sParam + 384 + fL),  bbH = *(const f32x4*)(sParam + 384 + fH); \
    f32x4 hL = tanh4(sp4(xt) * wtL + sp4(xx) * wxL + sp4(xy) * wyL + bbL); \
    f32x4 hH = tanh4(sp4(xt) * wtH + sp4(xx) * wxH + sp4(xy) * wyH + bbH); \
    f32x4 aL = sp4(1.f) - hL * hL, aH = sp4(1.f) - hH * hH; \
    h1F.K = packB(hL, hH); \
    t1t.K = packB(aL * wtL, aH * wtH); \
    t1x.K = packB(aL * wxL, aH * wxH); \
    t1y.K = packB(aL * wyL, aH * wyH); \
    s1x.K = packB((sp4(0.f) - hL) * aL * wxL * wxL, (sp4(0.f) - hH) * aH * wxH * wxH); \
    s1y.K = packB((sp4(0.f) - hL) * aL * wyL * wyL, (sp4(0.f) - hH) * aH * wyH * wyH); }
        SEED(k0, 0, 4) SEED(k1, 1, 5) SEED(k2, 2, 6) SEED(k3, 3, 7)
#undef SEED

        // ---- layer 2 (ONE panel pass): z2 | tz2t | tz2x | tz2y | sz2x | sz2y ----
        Acc8x6 R6 = gemm6_frag(pW2f, c, g, h1F, t1t, t1x, t1y, s1x, s1y,
                               acc_bias(sParam + 4 * 128, fb),
                               acc_zero(), acc_zero(), acc_zero(),
                               acc_zero(), acc_zero());

        // ---- FUSED layer-2 post (one pass over 6 accs) ----
        Frag h2F, t2t, txF, tyF, s2xF, s2yF;
#define POST2(K, NL, NH) { \
    f32x4 hL = tanh4(R6.a.NL), hH = tanh4(R6.a.NH); \
    f32x4 aL = sp4(1.f) - hL * hL, aH = sp4(1.f) - hH * hH; \
    h2F.K = packB(hL, hH); \
    t2t.K = packB(aL * R6.b.NL, aH * R6.b.NH); \
    f32x4 txL = aL * R6.c.NL, txH = aH * R6.c.NH; \
    txF.K = packB(txL, txH); \
    f32x4 pxL = (sp4(0.f) - hL) * txL * R6.c.NL, pxH = (sp4(0.f) - hH) * txH * R6.c.NH; \
    f32x4 tyL = aL * R6.d.NL, tyH = aH * R6.d.NH; \
    tyF.K = packB(tyL, tyH); \
    f32x4 pyL = (sp4(0.f) - hL) * tyL * R6.d.NL, pyH = (sp4(0.f) - hH) * tyH * R6.d.NH; \
    s2xF.K = packB(aL * R6.e.NL + pxL, aH * R6.e.NH + pxH); \
    s2yF.K = packB(aL * R6.f.NL + pyL, aH * R6.f.NH + pyH); }
        POST2(k0, n0, n4) POST2(k1, n1, n5) POST2(k2, n2, n6) POST2(k3, n3, n7)
#undef POST2

        // ---- layer 3 (ONE panel pass): z3 | tz3t | tz3x | tz3y | sz3x | sz3y ----
        R6 = gemm6_frag(pW3f, c, g, h2F, t2t, txF, tyF, s2xF, s2yF,
                        acc_bias(sParam + 5 * 128, fb),
                        acc_zero(), acc_zero(), acc_zero(),
                        acc_zero(), acc_zero());

        // ---- FUSED layer-3 dots (one pass) ----
        {
            f32x4 scp = sp4(0.f), sc1t = sp4(0.f);
            f32x4 srxa = sp4(0.f), srxb = sp4(0.f);
            f32x4 srya = sp4(0.f), sryb = sp4(0.f);
            f32x4 sc2x = sp4(0.f), sc2y = sp4(0.f);
#define DOTS(NL, NH, IL, IH) { \
    f32x4 w4L = *(const f32x4*)(w4p + (IL) * 16 + fb); \
    f32x4 w4H = *(const f32x4*)(w4p + (IH) * 16 + fb); \
    f32x4 hL = tanh4(R6.a.NL), hH = tanh4(R6.a.NH); \
    f32x4 waL = w4L * (sp4(1.f) - hL * hL), waH = w4H * (sp4(1.f) - hH * hH); \
    scp  += w4L * hL + w4H * hH; \
    sc1t += waL * R6.b.NL + waH * R6.b.NH; \
    f32x4 wtxL = waL * R6.c.NL, wtxH = waH * R6.c.NH; \
    srxa += wtxL + wtxH; \
    srxb -= wtxL * hL * R6.c.NL + wtxH * hH * R6.c.NH; \
    f32x4 wtyL = waL * R6.d.NL, wtyH = waH * R6.d.NH; \
    srya += wtyL + wtyH; \
    sryb -= wtyL * hL * R6.d.NL + wtyH * hH * R6.d.NH; \
    sc2x += waL * R6.e.NL + waH * R6.e.NH; \
    sc2y += waL * R6.f.NL + waH * R6.f.NH; }
            DOTS(n0, n4, 0, 4) DOTS(n1, n5, 1, 5) DOTS(n2, n6, 2, 6) DOTS(n3, n7, 3, 7)
#undef DOTS
            float cp  = red16(hsum4(scp));
            float c1t = red16(hsum4(sc1t));
            float c1x = red16(hsum4(srxa));
            float c1y = red16(hsum4(srya));
            float c2x = red16(hsum4(srxb) + hsum4(sc2x));
            float c2y = red16(hsum4(sryb) + hsum4(sc2y));
            if (lane < 16) {
                out[sbase + lane]           = cp + b4;
                out[(long)N + sbase + lane] = c1t;
                out[2L * N + sbase + lane]  = c1x;
                out[3L * N + sbase + lane]  = c1y;
                out[4L * N + sbase + lane]  = 2.f * c2x;
                out[5L * N + sbase + lane]  = 2.f * c2y;
            }
        }
    }
}

extern "C" void kernel_launch(void* const* d_in, const int* in_sizes, int n_in,
                              void* d_out, int out_size, void* d_ws, size_t ws_size,
                              hipStream_t stream) {
    const float* X  = (const float*)d_in[0];
    const float* W1 = (const float*)d_in[1];
    const float* B1 = (const float*)d_in[2];
    const float* W2 = (const float*)d_in[3];
    const float* B2 = (const float*)d_in[4];
    const float* W3 = (const float*)d_in[5];
    const float* B3 = (const float*)d_in[6];
    const float* W4 = (const float*)d_in[7];
    const float* B4 = (const float*)d_in[8];
    float* out = (float*)d_out;
    const int N = in_sizes[0] / 3;

    mlp_jet_kernel<<<NBLK, TPB, 0, stream>>>(X, W1, B1, W2, B2, W3, B3, W4, B4, out, N);
}